// Round 1
// baseline (178.373 us; speedup 1.0000x reference)
//
#include <hip/hip_runtime.h>

// VMamba SS2D block, fp32. B=128, spatial 8x8 (L=64), DI=256, K=4 dirs, G=4 groups,
// Dg=64, N=6 state, dt-rank 6.
//
// ws layout (floats): xc2[128*64*256] | xflat_t[128*64*256] | y_t[128*4*64*256]
// z is stored in d_out (K1 writes it, K5 consumes then overwrites with final out).

#define DEV __device__ __forceinline__

DEV float fast_silu(float x) { return x / (1.f + __expf(-x)); }
DEV float fast_softplus(float x) {
    return fmaxf(x, 0.f) + __logf(1.f + __expf(-fabsf(x)));
}

// ---------------- K1: z[b][l][e] = silu(sum_d x_in[b,l,d] * w[e,d]) ----------------
__global__ __launch_bounds__(256) void k1_inproj(const float* __restrict__ x_in,
                                                 const float* __restrict__ w,
                                                 float* __restrict__ z) {
    __shared__ float xr[8][256];
    const int blk = blockIdx.x;              // b*8 + lg
    const int b = blk >> 3, l0 = (blk & 7) * 8;
    const int tid = threadIdx.x;
    const float* xbase = x_in + (b * 64 + l0) * 256;
    for (int idx = tid; idx < 8 * 256; idx += 256)
        xr[idx >> 8][idx & 255] = xbase[idx];
    __syncthreads();
    float acc[8];
#pragma unroll
    for (int p = 0; p < 8; p++) acc[p] = 0.f;
    const float* wrow = w + tid * 256;       // in_proj_w[e][d], row contiguous in d
    for (int d0 = 0; d0 < 256; d0 += 4) {
        float4 w4 = *reinterpret_cast<const float4*>(wrow + d0);
#pragma unroll
        for (int p = 0; p < 8; p++) {
            float4 x4 = *reinterpret_cast<const float4*>(&xr[p][d0]);
            acc[p] += x4.x * w4.x + x4.y * w4.y + x4.z * w4.z + x4.w * w4.w;
        }
    }
    float* zbase = z + (b * 64 + l0) * 256;
#pragma unroll
    for (int p = 0; p < 8; p++) zbase[p * 256 + tid] = fast_silu(acc[p]);
}

// ---------------- K2: depthwise 3x3 SAME conv + bias + silu ----------------
// x_[b,c,H,W] = x_in[b, H>>3, W>>3, c*64 + (H&7)*8 + (W&7)]
// output xc2[b][i][j][c][dh][dw]  (patch-major, 256 contiguous per patch)
__global__ __launch_bounds__(256) void k2_dwconv(const float* __restrict__ x_in,
                                                 const float* __restrict__ cw,
                                                 const float* __restrict__ cb,
                                                 float* __restrict__ xc2) {
    const int blk = blockIdx.x;              // b*64 + pi*8 + pj
    const int b = blk >> 6, pi = (blk >> 3) & 7, pj = blk & 7;
    const int tid = threadIdx.x;             // c*64 + dh*8 + dw
    const int c = tid >> 6, dh = (tid >> 3) & 7, dw = tid & 7;
    const int H = pi * 8 + dh, W = pj * 8 + dw;
    float acc = cb[c];
#pragma unroll
    for (int u = 0; u < 3; u++) {
        int Hp = H + u - 1;
        if (Hp < 0 || Hp > 63) continue;
#pragma unroll
        for (int v = 0; v < 3; v++) {
            int Wp = W + v - 1;
            if (Wp < 0 || Wp > 63) continue;
            float xv = x_in[((b * 8 + (Hp >> 3)) * 8 + (Wp >> 3)) * 256 +
                            c * 64 + ((Hp & 7) << 3) + (Wp & 7)];
            acc += xv * cw[c * 9 + u * 3 + v];
        }
    }
    xc2[blk * 256 + tid] = fast_silu(acc);
}

// ---------------- K3: patch embed GEMM + bias + BN -> xflat_t[b][l][e] ----------------
__global__ __launch_bounds__(256) void k3_patch_bn(const float* __restrict__ xc2,
                                                   const float* __restrict__ pw,
                                                   const float* __restrict__ pb,
                                                   const float* __restrict__ gamma,
                                                   const float* __restrict__ beta,
                                                   const float* __restrict__ mean,
                                                   const float* __restrict__ var,
                                                   float* __restrict__ xflat_t) {
    __shared__ float xr[8][256];
    const int blk = blockIdx.x;
    const int b = blk >> 3, l0 = (blk & 7) * 8;
    const int tid = threadIdx.x;
    const float* xbase = xc2 + (b * 64 + l0) * 256;
    for (int idx = tid; idx < 8 * 256; idx += 256)
        xr[idx >> 8][idx & 255] = xbase[idx];
    __syncthreads();
    float acc[8];
#pragma unroll
    for (int p = 0; p < 8; p++) acc[p] = 0.f;
    const float* wrow = pw + tid * 256;      // patch_w[e][c][dh][dw] contiguous
    for (int d0 = 0; d0 < 256; d0 += 4) {
        float4 w4 = *reinterpret_cast<const float4*>(wrow + d0);
#pragma unroll
        for (int p = 0; p < 8; p++) {
            float4 x4 = *reinterpret_cast<const float4*>(&xr[p][d0]);
            acc[p] += x4.x * w4.x + x4.y * w4.y + x4.z * w4.z + x4.w * w4.w;
        }
    }
    const float sc = rsqrtf(var[tid] + 1e-5f) * gamma[tid];
    const float sh = beta[tid] - mean[tid] * sc;
    const float bias = pb[tid];
    float* obase = xflat_t + (b * 64 + l0) * 256;
#pragma unroll
    for (int p = 0; p < 8; p++) {
        float v = acc[p] + bias;
        obase[p * 256 + tid] = v * sc + sh;
    }
}

// ---------------- K4: per-(b,k,g) projection + selective scan ----------------
// writes y_t[b][k][l][e]  (e = g*64+d contiguous)
__global__ __launch_bounds__(256) void k4_scan(const float* __restrict__ xflat_t,
                                               const float* __restrict__ xpw_g,
                                               const float* __restrict__ dt_w,
                                               const float* __restrict__ dt_b,
                                               const float* __restrict__ A_logs,
                                               const float* __restrict__ Ds,
                                               float* __restrict__ y_t) {
    __shared__ float xg[64][65];     // [d][l], pad 65 -> conflict-free
    __shared__ float xdbl[18 * 64];  // [c][l]
    __shared__ float xpw[18 * 64];   // [c][d]
    const int blk = blockIdx.x;      // b*16 + k*4 + g
    const int b = blk >> 4, k = (blk >> 2) & 3, g = blk & 3;
    const int tid = threadIdx.x;
    const int gk = g * 4 + k;

    // stage xg[d][l] = x_flat[b, g*64+d, lsrc(k,l)]
    for (int idx = tid; idx < 4096; idx += 256) {
        int d = idx & 63, l = idx >> 6;
        int t = ((l & 7) << 3) | (l >> 3);
        int ls;
        if (k == 0) ls = l;
        else if (k == 1) ls = t;
        else if (k == 2) ls = 63 - l;
        else { int lf = 63 - l; ls = ((lf & 7) << 3) | (lf >> 3); }
        xg[d][l] = xflat_t[(b * 64 + ls) * 256 + g * 64 + d];
    }
    for (int idx = tid; idx < 18 * 64; idx += 256)
        xpw[idx] = xpw_g[gk * 18 * 64 + idx];
    __syncthreads();

    // x_dbl[c][l] = sum_d xg[d][l] * xpw[c][d]
    for (int t = tid; t < 18 * 64; t += 256) {
        int c = t >> 6, l = t & 63;
        const float* wr = &xpw[c * 64];
        float s = 0.f;
#pragma unroll 8
        for (int d = 0; d < 64; d++) s += xg[d][l] * wr[d];
        xdbl[c * 64 + l] = s;
    }
    __syncthreads();

    if (tid < 64) {
        const int d = tid;
        float dtw[6], Av[6];
#pragma unroll
        for (int r = 0; r < 6; r++) dtw[r] = dt_w[(gk * 64 + d) * 6 + r];
#pragma unroll
        for (int n = 0; n < 6; n++) Av[n] = -__expf(A_logs[(gk * 64 + d) * 6 + n]);
        const float dtb = dt_b[gk * 64 + d];
        const float Dsv = Ds[gk * 64 + d];
        float h[6];
#pragma unroll
        for (int n = 0; n < 6; n++) h[n] = 0.f;
        float* ybase = y_t + ((size_t)(b * 4 + k) * 64) * 256 + g * 64 + d;
        for (int l = 0; l < 64; l++) {
            float xv = xg[d][l];
            float delta = dtb;
#pragma unroll
            for (int r = 0; r < 6; r++) delta += xdbl[r * 64 + l] * dtw[r];
            delta = fast_softplus(delta);
            float dxu = delta * xv;
            float y = 0.f;
#pragma unroll
            for (int n = 0; n < 6; n++) {
                float Bv = xdbl[(6 + n) * 64 + l];
                float Cv = xdbl[(12 + n) * 64 + l];
                h[n] = __expf(delta * Av[n]) * h[n] + dxu * Bv;
                y += h[n] * Cv;
            }
            ybase[l * 256] = y + Dsv * xv;
        }
    }
}

// ---------------- K5: combine 4 dirs + LayerNorm + z-gate + out_proj ----------------
__global__ __launch_bounds__(256) void k5_out(const float* __restrict__ y_t,
                                              const float* zp,            // aliases out!
                                              const float* __restrict__ lng,
                                              const float* __restrict__ lnb,
                                              const float* __restrict__ ow,
                                              float* outp) {
    __shared__ float ylr[8][256];
    __shared__ float scratch[8];
    const int blk = blockIdx.x;
    const int b = blk >> 3, l0 = (blk & 7) * 8;
    const int tid = threadIdx.x;
    const float gma = lng[tid], bta = lnb[tid];
    const float* ybase = y_t + (size_t)b * 4 * 64 * 256;
    for (int p = 0; p < 8; p++) {
        int l = l0 + p;
        int t = ((l & 7) << 3) | (l >> 3);
        float v = ybase[(0 * 64 + l) * 256 + tid]
                + ybase[(2 * 64 + (63 - l)) * 256 + tid]
                + ybase[(1 * 64 + t) * 256 + tid]
                + ybase[(3 * 64 + (63 - t)) * 256 + tid];
        float a = v, sq = v * v;
#pragma unroll
        for (int off = 32; off; off >>= 1) {
            a += __shfl_down(a, off, 64);
            sq += __shfl_down(sq, off, 64);
        }
        if ((tid & 63) == 0) { scratch[tid >> 6] = a; scratch[4 + (tid >> 6)] = sq; }
        __syncthreads();
        float mu = (scratch[0] + scratch[1] + scratch[2] + scratch[3]) * (1.f / 256.f);
        float ms = (scratch[4] + scratch[5] + scratch[6] + scratch[7]) * (1.f / 256.f);
        float inv = rsqrtf(ms - mu * mu + 1e-5f);
        float yn = (v - mu) * inv * gma + bta;
        ylr[p][tid] = yn * zp[(b * 64 + l) * 256 + tid];
        __syncthreads();
    }
    float acc[8];
#pragma unroll
    for (int p = 0; p < 8; p++) acc[p] = 0.f;
    const float* wrow = ow + tid * 256;      // out_proj_w[d][e] contiguous in e
    for (int e0 = 0; e0 < 256; e0 += 4) {
        float4 w4 = *reinterpret_cast<const float4*>(wrow + e0);
#pragma unroll
        for (int p = 0; p < 8; p++) {
            float4 x4 = *reinterpret_cast<const float4*>(&ylr[p][e0]);
            acc[p] += x4.x * w4.x + x4.y * w4.y + x4.z * w4.z + x4.w * w4.w;
        }
    }
    float* obase = outp + (b * 64 + l0) * 256;
#pragma unroll
    for (int p = 0; p < 8; p++) obase[p * 256 + tid] = acc[p];
}

extern "C" void kernel_launch(void* const* d_in, const int* in_sizes, int n_in,
                              void* d_out, int out_size, void* d_ws, size_t ws_size,
                              hipStream_t stream) {
    (void)in_sizes; (void)n_in; (void)out_size; (void)ws_size;
    const float* x_in      = (const float*)d_in[0];
    const float* in_proj_w = (const float*)d_in[1];
    const float* conv_w    = (const float*)d_in[2];
    const float* conv_b    = (const float*)d_in[3];
    const float* patch_w   = (const float*)d_in[4];
    const float* patch_b   = (const float*)d_in[5];
    const float* bn_gamma  = (const float*)d_in[6];
    const float* bn_beta   = (const float*)d_in[7];
    const float* bn_mean   = (const float*)d_in[8];
    const float* bn_var    = (const float*)d_in[9];
    const float* x_proj_w  = (const float*)d_in[10];
    const float* dt_w      = (const float*)d_in[11];
    const float* dt_b      = (const float*)d_in[12];
    const float* A_logs    = (const float*)d_in[13];
    const float* Ds        = (const float*)d_in[14];
    const float* ln_gamma  = (const float*)d_in[15];
    const float* ln_beta   = (const float*)d_in[16];
    const float* out_proj_w= (const float*)d_in[17];

    float* out = (float*)d_out;
    float* ws  = (float*)d_ws;
    float* xc2     = ws;                 // 2,097,152 floats
    float* xflat_t = ws + 2097152;       // 2,097,152 floats
    float* y_t     = ws + 4194304;       // 8,388,608 floats
    float* z = out;                      // d_out doubles as z scratch

    hipLaunchKernelGGL(k1_inproj, dim3(1024), dim3(256), 0, stream, x_in, in_proj_w, z);
    hipLaunchKernelGGL(k2_dwconv, dim3(8192), dim3(256), 0, stream, x_in, conv_w, conv_b, xc2);
    hipLaunchKernelGGL(k3_patch_bn, dim3(1024), dim3(256), 0, stream,
                       xc2, patch_w, patch_b, bn_gamma, bn_beta, bn_mean, bn_var, xflat_t);
    hipLaunchKernelGGL(k4_scan, dim3(2048), dim3(256), 0, stream,
                       xflat_t, x_proj_w, dt_w, dt_b, A_logs, Ds, y_t);
    hipLaunchKernelGGL(k5_out, dim3(1024), dim3(256), 0, stream,
                       y_t, z, ln_gamma, ln_beta, out_proj_w, out);
}